// Round 3
// baseline (232.759 us; speedup 1.0000x reference)
//
#include <hip/hip_runtime.h>

// WindowSlice: B=64, T=4096, C=128 fp32. L = ceil(0.9*T) = 3687.
// out[b,i,c] = lerp(x[b, starts[b]+lo(i), c], x[b, starts[b]+lo(i)+1, c], w(i))
// where t = clip(i * L/(T-1), 0, L-1), lo = min(floor(t), L-2), w = t - lo.
//
// v3: LDS-staged single-fetch. Theory: the vlo/vhi overlap (every input row
// read by ~2 output rows) is NOT being collapsed by the caches -> 402 MB HBM
// traffic (62 us at 6.5 TB/s, matching the observed residual). Stage each
// block's input window into LDS exactly once via global_load_lds:
//   - block = 32 output rows; lo-span <= 28 (+1 hi) -> stage 32 input rows
//     (16 KB LDS, linear layout as global_load_lds requires; 8 blocks/CU).
//   - staged HBM reads = 8192 * 16 KB = 134 MB (vs 268 MB double-fetch).
//   - both vlo and vhi served from LDS (conflict-free ds_read_b128 pattern).
// Interp math unchanged (double) -> bit-identical output to v2.

constexpr int B_ = 64;
constexpr int T_ = 4096;
constexpr int C_ = 128;
constexpr int L_ = 3687;            // ceil(0.9 * 4096)
constexpr int C4 = C_ / 4;          // 32 float4 per row
constexpr int ROWS_OUT = 32;        // output rows per block
constexpr int ROWS_IN  = 32;        // staged input rows (need <= 30)
constexpr int NBLK = B_ * T_ / ROWS_OUT;             // 8192 (divisible by 8)
constexpr int BLOCKS_PER_B = T_ / ROWS_OUT;          // 128
constexpr int NXCD = 8;

typedef float f32x4 __attribute__((ext_vector_type(4)));
typedef __attribute__((address_space(3))) void       lds_void;
typedef __attribute__((address_space(1))) const void glob_void;

__global__ __launch_bounds__(256, 8)
void WindowSlice_kernel(const float4* __restrict__ x,
                        const int*    __restrict__ starts,
                        float4*       __restrict__ out) {
    __shared__ float4 lds[ROWS_IN * C4];   // 16 KB, linear (global_load_lds dest)

    // Bijective XCD-chunked swizzle (NBLK % 8 == 0): consecutive blocks share
    // one boundary input row; keep them on the same XCD's L2.
    const int bid = blockIdx.x;
    const int swz = (bid & (NXCD - 1)) * (NBLK / NXCD) + (bid >> 3);

    const int b  = swz >> 7;                          // / BLOCKS_PER_B (uniform)
    const int i0 = (swz & (BLOCKS_PER_B - 1)) * ROWS_OUT;

    const int start = starts[b];                      // block-uniform -> s_load

    // Block's staging base row: m0 = lo(i0), exact integer floor.
    // i0*L_ <= 4064*3687 = 14,983,968 < 2^31; gcd analysis shows the integer
    // floor equals the double-path floor for all i.
    const int m0 = (i0 * L_) / (T_ - 1);

    const long long xrow0 = ((long long)b * T_ + start) * C4;  // f4 idx of local row 0

    // --- stage 32 input rows (rows m0..m0+31, clamped to L-1) into LDS ---
    #pragma unroll
    for (int k = 0; k < 4; ++k) {
        const int idx = k * 256 + threadIdx.x;        // 0..1023 float4 slots
        const int r   = idx >> 5;                     // staged row 0..31
        const int c   = idx & 31;
        int g = m0 + r;                               // global local-window row
        if (g > L_ - 1) g = L_ - 1;                   // tail clamp (dup rows, unused)
        const float4* src = x + (xrow0 + (long long)g * C4 + c);
        // LDS dest = wave-uniform base + lane*16 (idx is lane-linear) -> legal.
        __builtin_amdgcn_global_load_lds((glob_void*)src,
                                         (lds_void*)&lds[idx], 16, 0, 0);
    }
    __syncthreads();

    // --- compute 4 output rows per thread from LDS ---
    const int c4 = threadIdx.x & 31;
    const int r0 = threadIdx.x >> 5;                  // 0..7
    const double step = (double)L_ / (double)(T_ - 1);

    f32x4* outv = (f32x4*)out;
    const long long obase = ((long long)b * T_ + i0) * C4 + c4;

    #pragma unroll
    for (int q = 0; q < 4; ++q) {
        const int r = r0 + q * 8;                     // 0..31
        const int i = i0 + r;

        double t = (double)i * step;
        if (t > (double)(L_ - 1)) t = (double)(L_ - 1);
        int lo = (int)t;
        if (lo > L_ - 2) lo = L_ - 2;
        const float w = (float)(t - (double)lo);

        const int ll = lo - m0;                       // 0..28 within staged window
        const float4 vlo = lds[ll * C4 + c4];
        const float4 vhi = lds[(ll + 1) * C4 + c4];

        f32x4 o;
        o.x = fmaf(w, vhi.x - vlo.x, vlo.x);
        o.y = fmaf(w, vhi.y - vlo.y, vlo.y);
        o.z = fmaf(w, vhi.z - vlo.z, vlo.z);
        o.w = fmaf(w, vhi.w - vlo.w, vlo.w);

        __builtin_nontemporal_store(o, &outv[obase + (long long)r * C4]);
    }
}

extern "C" void kernel_launch(void* const* d_in, const int* in_sizes, int n_in,
                              void* d_out, int out_size, void* d_ws, size_t ws_size,
                              hipStream_t stream) {
    const float4* x      = (const float4*)d_in[0];
    const int*    starts = (const int*)d_in[1];
    float4*       out    = (float4*)d_out;

    WindowSlice_kernel<<<NBLK, 256, 0, stream>>>(x, starts, out);
}

// Round 4
// 226.548 us; speedup vs baseline: 1.0274x; 1.0274x over previous
//
#include <hip/hip_runtime.h>

// WindowSlice: B=64, T=4096, C=128 fp32. L = ceil(0.9*T) = 3687.
// out[b,i,c] = lerp(x[b, starts[b]+lo(i), c], x[b, starts[b]+lo(i)+1, c], w(i))
// where t = clip(i * L/(T-1), 0, L-1), lo = min(floor(t), L-2), w = t - lo.
//
// v4 = revert to v1 (measured best: 224.7 / 226.1 us).
// Post-mortem of the session's A/Bs:
//  - v2 (MLP=4, scalar starts, XCD swizzle, NT stores): 230.7 (-4.6 regress)
//  - v3 (LDS-staged guaranteed single-fetch, NT stores): 232.8 (-6.7 regress)
// Conclusions: input vlo/vhi reuse is already collapsed by L2 (forcing
// single-fetch changed nothing); L2 locality/swizzle is not a factor;
// NT stores forfeit L2 write-coalescing for no gain. The simple
// 1-float4/thread streaming form is at the mixed read+write HBM floor
// (~244 MiB irreducible traffic); remaining timed cost is harness fills.

constexpr int B_ = 64;
constexpr int T_ = 4096;
constexpr int C_ = 128;
constexpr int L_ = 3687;          // ceil(0.9 * 4096)
constexpr int C4 = C_ / 4;        // 32 float4 per row

__global__ __launch_bounds__(256)
void WindowSlice_kernel(const float4* __restrict__ x,
                        const int*    __restrict__ starts,
                        float4*       __restrict__ out) {
    const int tid = blockIdx.x * 256 + threadIdx.x;   // one float4 per thread
    const int row = tid >> 5;                         // / C4 (32)
    const int c4  = tid & 31;
    const int b   = row >> 12;                        // / T (4096)
    const int i   = row & (T_ - 1);

    // np.interp query point in double for robust lo/w (few F64 ops, negligible)
    const double step = (double)L_ / (double)(T_ - 1);
    double t = (double)i * step;
    if (t > (double)(L_ - 1)) t = (double)(L_ - 1);
    int lo = (int)t;
    if (lo > L_ - 2) lo = L_ - 2;
    const float w = (float)(t - (double)lo);

    const int start = starts[b];
    const long long base = ((long long)b * T_ + start + lo) * C4 + c4;

    const float4 vlo = x[base];
    const float4 vhi = x[base + C4];

    float4 o;
    o.x = fmaf(w, vhi.x - vlo.x, vlo.x);
    o.y = fmaf(w, vhi.y - vlo.y, vlo.y);
    o.z = fmaf(w, vhi.z - vlo.z, vlo.z);
    o.w = fmaf(w, vhi.w - vlo.w, vlo.w);

    out[(long long)row * C4 + c4] = o;
}

extern "C" void kernel_launch(void* const* d_in, const int* in_sizes, int n_in,
                              void* d_out, int out_size, void* d_ws, size_t ws_size,
                              hipStream_t stream) {
    const float4* x      = (const float4*)d_in[0];
    const int*    starts = (const int*)d_in[1];
    float4*       out    = (float4*)d_out;

    const int total_f4 = B_ * T_ * C4;               // 8,388,608
    const int blocks   = total_f4 / 256;             // 32,768
    WindowSlice_kernel<<<blocks, 256, 0, stream>>>(x, starts, out);
}